// Round 2
// baseline (210.301 us; speedup 1.0000x reference)
//
#include <hip/hip_runtime.h>
#include <math.h>

// Problem constants (match the reference)
constexpr int Bn = 32;
constexpr int Cn = 512;
constexpr int Tn = 1024;
constexpr int KS = 13;          // gaussian kernel size

// Tiling
constexpr int CB = 64;          // channels per block
constexpr int TT = 64;          // timesteps per chunk
constexpr int NSEG = 4;         // c-segments per block (256 threads / 64 t-cols)
constexpr int SEG = CB / NSEG;  // 16 output rows per conv thread
constexpr int DSTR = TT + 1;    // LDS row stride (odd -> conflict-free)

// One block per (b, c-block of 64). 256 threads:
//   conv phase : thread = (t-col 0..63, c-seg 0..3); sliding 13-tap fp32 window
//   recurrence : lanes 0..63 (wave 0) own one channel each, fp32, numpy op order
//   store      : all threads, coalesced rows
// ALL fp32 arithmetic uses explicit _rn intrinsics: one rounding per numpy op,
// no FMA contraction — bit-emulating the harness's float32 numpy reference.
__global__ __launch_bounds__(256)
void snn_fused(const float* __restrict__ x, const float* __restrict__ wp,
               float* __restrict__ out) {
  __shared__ float drv[CB][DSTR];   // 64*65*4 = 16.6 KB

  const int tid  = threadIdx.x;
  const int b    = blockIdx.y;
  const int c0   = blockIdx.x * CB;

  // ---- Gaussian weights, emulating numpy float32 semantics
  float kw[KS];
  {
    float w  = wp[0];
    float wc = fminf(fmaxf(w, 1.0f), 10.0f);        // clip(w, 1, 10)
    float sigma = __fadd_rn(5.5f, wc);              // 5.5 + clipped (= 11.0)
    float e[KS];
#pragma unroll
    for (int i = 0; i < KS; ++i) {
      float q = __fdiv_rn((float)(i - 6), sigma);   // fp32 correctly-rounded div
      float t = __fmul_rn(-0.5f, __fmul_rn(q, q));  // fp32 square, exact *-0.5
      e[i] = (float)exp((double)t);                 // ~correctly-rounded fp32 exp
    }
    // numpy pairwise_sum order for n=13:
    //   res = ((e0+e1)+(e2+e3)) + ((e4+e5)+(e6+e7)); then res += e8..e12
    float s = __fadd_rn(
        __fadd_rn(__fadd_rn(e[0], e[1]), __fadd_rn(e[2], e[3])),
        __fadd_rn(__fadd_rn(e[4], e[5]), __fadd_rn(e[6], e[7])));
    s = __fadd_rn(s, e[8]);
    s = __fadd_rn(s, e[9]);
    s = __fadd_rn(s, e[10]);
    s = __fadd_rn(s, e[11]);
    s = __fadd_rn(s, e[12]);
#pragma unroll
    for (int i = 0; i < KS; ++i) kw[i] = __fdiv_rn(e[i], s);
  }

  const int tl   = tid & (TT - 1);   // t within chunk
  const int cseg = tid >> 6;         // 0..3 : which 16-row segment
  const long xbase = (long)b * Cn * Tn;

  float mem = 0.0f;                  // recurrence state (wave 0 lanes only)

  for (int ch = 0; ch < Tn / TT; ++ch) {
    const int t0 = ch * TT;

    // ---------------- conv phase (all 256 threads) ----------------
    {
      float win[KS];
#pragma unroll
      for (int m = 0; m < KS; ++m) win[m] = 0.0f;

      const int cin0 = c0 + cseg * SEG - 6;     // first input channel, this seg
#pragma unroll
      for (int j = 0; j < SEG + KS - 1; ++j) {  // 28 input rows
        const int gc = cin0 + j;
        float v = 0.0f;
        if (gc >= 0 && gc < Cn)                 // zero padding
          v = x[xbase + (long)gc * Tn + t0 + tl];
#pragma unroll
        for (int m = 0; m < KS - 1; ++m) win[m] = win[m + 1];
        win[KS - 1] = v;
        if (j >= KS - 1) {
          // x_mean: sequential ascending, separate mul/add roundings (no FMA)
          float acc = __fmul_rn(kw[0], win[0]);
#pragma unroll
          for (int i = 1; i < KS; ++i)
            acc = __fadd_rn(acc, __fmul_rn(kw[i], win[i]));
          const int r = cseg * SEG + (j - (KS - 1));
          drv[r][tl] = __fsub_rn(win[6], acc);  // drive = x - x_mean
        }
      }
    }
    __syncthreads();

    // ---------------- recurrence phase (wave 0) ----------------
    if (tid < CB) {
      const int c = tid;
      for (int t = 0; t < TT; ++t) {
        const float d = drv[c][t];
        // reset uses mem BEFORE update; numpy op order:
        //   mem = ((BETA*mem) + xt) - (reset*THR), each op rounded, no FMA
        const float rthr = (mem > 0.5f) ? 0.5f : 0.0f;
        float a = __fmul_rn(0.95f, mem);
        float bb = __fadd_rn(a, d);
        mem = __fsub_rn(bb, rthr);
        drv[c][t] = (mem > 0.5f) ? 1.0f : 0.0f;   // forward of _atan_spike
      }
    }
    __syncthreads();

    // ---------------- store phase (all threads, coalesced) ----------------
    for (int i = tid; i < CB * TT; i += 256) {
      const int r = i >> 6;        // channel row
      const int t = i & (TT - 1);  // consecutive lanes -> consecutive t
      out[xbase + (long)(c0 + r) * Tn + t0 + t] = drv[r][t];
    }
    __syncthreads();               // drv reused next chunk
  }
}

extern "C" void kernel_launch(void* const* d_in, const int* in_sizes, int n_in,
                              void* d_out, int out_size, void* d_ws, size_t ws_size,
                              hipStream_t stream) {
  const float* x  = (const float*)d_in[0];
  const float* w  = (const float*)d_in[1];
  float* out      = (float*)d_out;
  dim3 grid(Cn / CB, Bn, 1);
  snn_fused<<<grid, 256, 0, stream>>>(x, w, out);
}

// Round 3
// 133.329 us; speedup vs baseline: 1.5773x; 1.5773x over previous
//
#include <hip/hip_runtime.h>
#include <math.h>

// Problem constants
constexpr int Bn = 32;
constexpr int Cn = 512;
constexpr int Tn = 1024;
constexpr int KS = 13;

// Tiling
constexpr int CB   = 64;          // channels per block
constexpr int TT   = 64;          // timesteps per chunk
constexpr int NCH  = Tn / TT;     // 16 chunks
constexpr int DSTR = TT + 1;      // LDS row stride (odd -> conflict-free)
constexpr int NL   = 34;          // loads per conv thread (22 rows + 12 halo)

// 256 blocks (32 b x 8 c-groups) x 256 threads = 1 block/CU.
// Software pipeline across T-chunks:
//   wave 0    : store spikes chunk k-1 (coalesced via LDS) + scan chunk k
//   waves 1-3 : prefetch x for chunk k+2 into regs, conv chunk k+1 -> D
// One barrier per iteration. All fp32 math uses explicit _rn intrinsics
// (one rounding per numpy op, no FMA) — bit-identical to the round-2 kernel
// that validated at absmax 0.0.
__global__ __launch_bounds__(256, 1)
void snn_fused(const float* __restrict__ x, const float* __restrict__ wp,
               float* __restrict__ out) {
  __shared__ float D[2][CB][DSTR];  // drive tiles, double buffered (33.3 KB)
  __shared__ float S[CB][DSTR];     // spike tile, wave0-private   (16.6 KB)

  const int tid = threadIdx.x;
  const int b   = blockIdx.y;
  const int c0  = blockIdx.x * CB;
  const long xbase = (long)b * Cn * Tn;

  // ---- Gaussian weights, emulating numpy float32 semantics (validated) ----
  float kw[KS];
  {
    float w  = wp[0];
    float wc = fminf(fmaxf(w, 1.0f), 10.0f);        // clip(w, 1, 10)
    float sigma = __fadd_rn(5.5f, wc);              // 5.5 + clipped
    float e[KS];
#pragma unroll
    for (int i = 0; i < KS; ++i) {
      float q = __fdiv_rn((float)(i - 6), sigma);
      float t = __fmul_rn(-0.5f, __fmul_rn(q, q));
      e[i] = (float)exp((double)t);
    }
    // numpy pairwise_sum order for n=13
    float s = __fadd_rn(
        __fadd_rn(__fadd_rn(e[0], e[1]), __fadd_rn(e[2], e[3])),
        __fadd_rn(__fadd_rn(e[4], e[5]), __fadd_rn(e[6], e[7])));
    s = __fadd_rn(s, e[8]);  s = __fadd_rn(s, e[9]);  s = __fadd_rn(s, e[10]);
    s = __fadd_rn(s, e[11]); s = __fadd_rn(s, e[12]);
#pragma unroll
    for (int i = 0; i < KS; ++i) kw[i] = __fdiv_rn(e[i], s);
  }

  const bool convw = (tid >= 64);          // waves 1..3 do conv
  const int  tl    = tid & 63;             // t-column (conv/store) or channel (scan)
  const int  segS  = convw ? ((tid >> 6) - 1) * 21 : 0;   // 0, 21, 42
  const int  cin0  = c0 + segS - 6;        // first input channel for this seg

  float xp[NL], xn[NL];                    // x prefetch double-buffer (regs)

  auto load_chunk = [&](int m, float* dst) {
#pragma unroll
    for (int j = 0; j < NL; ++j) {
      const int gc = cin0 + j;
      float v = 0.0f;
      if (gc >= 0 && gc < Cn)              // zero padding, wave-uniform branch
        v = x[xbase + (long)gc * Tn + m * TT + tl];
      dst[j] = v;
    }
  };
  // conv from xp: output rows segS..segS+21; identical op order to round 2
  auto conv_chunk = [&](int parity) {
#pragma unroll
    for (int r = 0; r < 22; ++r) {
      float acc = __fmul_rn(kw[0], xp[r]);
#pragma unroll
      for (int i = 1; i < KS; ++i)
        acc = __fadd_rn(acc, __fmul_rn(kw[i], xp[r + i]));
      D[parity][segS + r][tl] = __fsub_rn(xp[r + 6], acc);  // x - x_mean
    }
  };

  // ---------------- prologue: fill D[0] (chunk 0), prefetch chunk 1 --------
  if (convw) {
    load_chunk(0, xp);
    load_chunk(1, xn);
    conv_chunk(0);
#pragma unroll
    for (int j = 0; j < NL; ++j) xp[j] = xn[j];
  }
  __syncthreads();

  float mem = 0.0f;                        // recurrence state (wave 0)

  for (int k = 0; k < NCH; ++k) {
    if (!convw) {
      // ---- store spikes of chunk k-1 (S still holds them; in-order LDS
      //      reads precede this iteration's scan writes within the wave)
      if (k > 0) {
        const int t0p = (k - 1) * TT;
#pragma unroll 8
        for (int r = 0; r < CB; ++r)
          out[xbase + (long)(c0 + r) * Tn + t0p + tl] = S[r][tl];
      }
      // ---- scan chunk k (lane = channel), batch-prefetch 8 drive values
      const int c = tl;
      float (*Dc)[DSTR] = D[k & 1];
      for (int tt = 0; tt < TT; tt += 8) {
        float dv[8];
#pragma unroll
        for (int j = 0; j < 8; ++j) dv[j] = Dc[c][tt + j];
#pragma unroll
        for (int j = 0; j < 8; ++j) {
          const float rthr = (mem > 0.5f) ? 0.5f : 0.0f;   // reset from OLD mem
          float a  = __fmul_rn(0.95f, mem);
          float s2 = __fadd_rn(a, dv[j]);
          mem = __fsub_rn(s2, rthr);
          S[c][tt + j] = (mem > 0.5f) ? 1.0f : 0.0f;       // hard spike fwd
        }
      }
    } else {
      // ---- conv waves: prefetch chunk k+2, conv chunk k+1
      if (k + 2 < NCH) load_chunk(k + 2, xn);
      if (k + 1 < NCH) {
        conv_chunk((k + 1) & 1);
#pragma unroll
        for (int j = 0; j < NL; ++j) xp[j] = xn[j];
      }
    }
    __syncthreads();
  }

  // ---------------- epilogue: store chunk 15 spikes ------------------------
  if (!convw) {
    const int t0p = (NCH - 1) * TT;
#pragma unroll 8
    for (int r = 0; r < CB; ++r)
      out[xbase + (long)(c0 + r) * Tn + t0p + tl] = S[r][tl];
  }
}

extern "C" void kernel_launch(void* const* d_in, const int* in_sizes, int n_in,
                              void* d_out, int out_size, void* d_ws, size_t ws_size,
                              hipStream_t stream) {
  const float* x  = (const float*)d_in[0];
  const float* w  = (const float*)d_in[1];
  float* out      = (float*)d_out;
  dim3 grid(Cn / CB, Bn, 1);
  snn_fused<<<grid, 256, 0, stream>>>(x, w, out);
}